// Round 22
// baseline (274.771 us; speedup 1.0000x reference)
//
#include <hip/hip_runtime.h>
#include <math.h>

#define S_LEN 2048
#define BATCH 2
#define EMB 768
#define NH 8
#define HD 96
#define NTOK (BATCH*S_LEN)
#define RSQRT_D 0.10206207261596575f   // 1/sqrt(96)

typedef unsigned short u16;
typedef __attribute__((ext_vector_type(8))) short bf16x8;
typedef __attribute__((ext_vector_type(4))) float f32x4;

#define MFMA16(a,b,c) __builtin_amdgcn_mfma_f32_16x16x32_bf16(a,b,c,0,0,0)

__device__ __forceinline__ u16 f2bf(float f){
    unsigned u = __float_as_uint(f);
    return (u16)((u + 0x7fffu + ((u>>16)&1u)) >> 16);
}
__device__ __forceinline__ float bf2f(unsigned u){
    return __uint_as_float(u << 16);
}

union U16x8 { u16 u[8]; float4 f4; };
union U16x4 { u16 u[4]; uint2 v2; };

// ---------------------------------------------------------------------------
// f32 -> bf16 elementwise convert (vectorized x4)
// ---------------------------------------------------------------------------
__global__ __launch_bounds__(256) void cvt_bf16_kernel(
    const float* __restrict__ src, u16* __restrict__ dst, int n4)
{
    int i = blockIdx.x * 256 + threadIdx.x;
    if (i < n4) {
        float4 v = ((const float4*)src)[i];
        U16x4 o;
        o.u[0] = f2bf(v.x); o.u[1] = f2bf(v.y); o.u[2] = f2bf(v.z); o.u[3] = f2bf(v.w);
        *(uint2*)(dst + (size_t)i*4) = o.v2;
    }
}

// ---------------------------------------------------------------------------
// 4x W[768][768] f32 -> Wt[n][k] bf16 (transpose + convert), one launch.
// ---------------------------------------------------------------------------
__global__ __launch_bounds__(256) void transcvt4_kernel(
    const float* __restrict__ W0, u16* __restrict__ T0,
    const float* __restrict__ W1, u16* __restrict__ T1,
    const float* __restrict__ W2, u16* __restrict__ T2,
    const float* __restrict__ W3, u16* __restrict__ T3)
{
    const float* W; u16* Wt;
    switch (blockIdx.z) {
        case 0:  W = W0; Wt = T0; break;
        case 1:  W = W1; Wt = T1; break;
        case 2:  W = W2; Wt = T2; break;
        default: W = W3; Wt = T3; break;
    }
    __shared__ float T[64][65];
    const int t = threadIdx.x;
    const int k0 = blockIdx.y * 64, n0 = blockIdx.x * 64;
    #pragma unroll
    for (int i = 0; i < 4; ++i) {
        int idx = t + 256*i;
        int r = idx >> 4, c4 = idx & 15;
        float4 v = *(const float4*)(W + (size_t)(k0 + r)*EMB + n0 + c4*4);
        T[r][c4*4+0] = v.x; T[r][c4*4+1] = v.y; T[r][c4*4+2] = v.z; T[r][c4*4+3] = v.w;
    }
    __syncthreads();
    #pragma unroll
    for (int i = 0; i < 2; ++i) {
        int idx = t + 256*i;
        int n = idx >> 3, c = idx & 7;
        U16x8 o;
        #pragma unroll
        for (int e = 0; e < 8; ++e) o.u[e] = f2bf(T[c*8+e][n]);
        *(float4*)(Wt + (size_t)(n0 + n)*EMB + k0 + c*8) = o.f4;
    }
}

// ---------------------------------------------------------------------------
// QKV projection MFMA (64x64 tile)
// ---------------------------------------------------------------------------
__global__ __launch_bounds__(256) void qkv_mfma_kernel(
    const u16* __restrict__ hsb,
    const u16* __restrict__ WqT, const float* __restrict__ bq,
    const u16* __restrict__ WkT, const float* __restrict__ bk,
    const u16* __restrict__ WvT, const float* __restrict__ bv,
    u16* __restrict__ qo, u16* __restrict__ ko, u16* __restrict__ vo)
{
    const u16* Wt; const float* bias; u16* out;
    if (blockIdx.z == 0)      { Wt = WqT; bias = bq; out = qo; }
    else if (blockIdx.z == 1) { Wt = WkT; bias = bk; out = ko; }
    else                      { Wt = WvT; bias = bv; out = vo; }

    __shared__ __align__(16) u16 As[64*64];
    __shared__ __align__(16) u16 Bs[64*64];
    const int tid = threadIdx.x;
    const int w = tid >> 6, lane = tid & 63, lh = lane & 15, g = lane >> 4;
    const int wm = w >> 1, wn = w & 1;
    const int row0 = blockIdx.y * 64, col0 = blockIdx.x * 64;

    f32x4 acc[2][2];
    #pragma unroll
    for (int i = 0; i < 2; ++i)
        #pragma unroll
        for (int j = 0; j < 2; ++j) acc[i][j] = (f32x4){0.f,0.f,0.f,0.f};

    for (int k0 = 0; k0 < EMB; k0 += 64) {
        __syncthreads();
        #pragma unroll
        for (int i = 0; i < 2; ++i) {
            int idx = tid + 256*i;
            int r = idx >> 3, c = idx & 7;
            float4 a4 = *(const float4*)(hsb + (size_t)(row0 + r)*EMB + k0 + c*8);
            *(float4*)(As + ((size_t)r*8 + (c ^ (r & 7)))*8) = a4;
            float4 b4 = *(const float4*)(Wt + (size_t)(col0 + r)*EMB + k0 + c*8);
            *(float4*)(Bs + ((size_t)r*8 + (c ^ (r & 7)))*8) = b4;
        }
        __syncthreads();
        bf16x8 af[2][2], bfr[2][2];
        #pragma unroll
        for (int mt = 0; mt < 2; ++mt)
            #pragma unroll
            for (int kk = 0; kk < 2; ++kk) {
                int r = wm*32 + mt*16 + lh;
                af[mt][kk] = *(const bf16x8*)(As + ((size_t)r*8 + ((kk*4+g) ^ (lh & 7)))*8);
            }
        #pragma unroll
        for (int nt = 0; nt < 2; ++nt)
            #pragma unroll
            for (int kk = 0; kk < 2; ++kk) {
                int r = wn*32 + nt*16 + lh;
                bfr[nt][kk] = *(const bf16x8*)(Bs + ((size_t)r*8 + ((kk*4+g) ^ (lh & 7)))*8);
            }
        #pragma unroll
        for (int mt = 0; mt < 2; ++mt)
            #pragma unroll
            for (int nt = 0; nt < 2; ++nt)
                #pragma unroll
                for (int kk = 0; kk < 2; ++kk)
                    acc[mt][nt] = MFMA16(af[mt][kk], bfr[nt][kk], acc[mt][nt]);
    }

    #pragma unroll
    for (int mt = 0; mt < 2; ++mt)
        #pragma unroll
        for (int nt = 0; nt < 2; ++nt)
            #pragma unroll
            for (int r = 0; r < 4; ++r) {
                int tt = row0 + wm*32 + mt*16 + g*4 + r;
                int o  = col0 + wn*32 + nt*16 + lh;
                float val = acc[mt][nt][r] + bias[o];
                int b = tt >> 11, s = tt & (S_LEN - 1);
                int h = o / HD, d = o - h*HD;
                out[((size_t)(b*NH + h)*S_LEN + s)*HD + d] = f2bf(val);
            }
}

// ---------------------------------------------------------------------------
// V transpose: vb[B,H,S,D] bf16 -> vt[B,H,D,S] bf16
// ---------------------------------------------------------------------------
__global__ __launch_bounds__(256) void vtrans_kernel(
    const u16* __restrict__ vb, u16* __restrict__ vt)
{
    const int bh = blockIdx.y;
    const int s0 = blockIdx.x * 64;
    __shared__ __align__(16) u16 T[64*96];
    const int t = threadIdx.x;
    #pragma unroll
    for (int i = 0; i < 3; ++i) {
        int idx = t + 256*i;
        int s = idx / 12, c = idx % 12;
        float4 v = *(const float4*)(vb + ((size_t)bh*S_LEN + s0 + s)*HD + c*8);
        *(float4*)(T + ((size_t)s*12 + c)*8) = v;
    }
    __syncthreads();
    #pragma unroll
    for (int i = 0; i < 3; ++i) {
        int idx = t + 256*i;
        int d = idx >> 3, c = idx & 7;
        U16x8 o;
        #pragma unroll
        for (int e = 0; e < 8; ++e) o.u[e] = T[(size_t)(c*8+e)*HD + d];
        *(float4*)(vt + ((size_t)bh*HD + d)*S_LEN + s0 + c*8) = o.f4;
    }
}

// ---------------------------------------------------------------------------
// Pass 1: l-only scores, T1 XCD swizzle: each XCD owns 2 bh values so each
// bh's K stream (re-read by 64 blocks) stays in one per-XCD L2.
// grid 1024 flat, 512 thr.
// ---------------------------------------------------------------------------
__global__ __launch_bounds__(512) void scores_l_kernel(
    const u16* __restrict__ qbf, const u16* __restrict__ kbf,
    const float* __restrict__ dist, const float* __restrict__ ang,
    const float* __restrict__ mask,
    const float* __restrict__ pdw, const float* __restrict__ pdb,
    const float* __restrict__ paw, const float* __restrict__ pab,
    float* __restrict__ lrow)
{
    // XCD-aware work remap (bijective over 1024 blocks)
    const int flat = blockIdx.y * 64 + blockIdx.x;
    const int xcd = flat & 7, jj = flat >> 3;
    const int bh = xcd*2 + (jj >> 6);
    const int q0 = (jj & 63) * 32;
    const int b = bh >> 3;
    const int tid = threadIdx.x;
    const int lane = tid & 63, w = tid >> 6, lh = lane & 15, g = lane >> 4;
    const int rt = w >> 2;
    const int ct = w & 3;

    __shared__ __align__(16) u16 Ks[64*96];
    __shared__ __align__(16) float Sf[32*68];

    const int kr_s = tid / 12, kc_s = tid - (tid / 12) * 12;
    const int kr2_s = (tid + 512) / 12, kc2_s = (tid + 512) - ((tid + 512) / 12) * 12;

    // prologue: stage Q (Sf region) + K0
    u16* Qtmp = (u16*)Sf;
    if (tid < 384) {
        int r = tid / 12, c = tid % 12;
        float4 v = *(const float4*)(qbf + ((size_t)bh*S_LEN + q0 + r)*HD + c*8);
        *(float4*)(Qtmp + ((size_t)r*12 + (c ^ ((r >> 1) & 3)))*8) = v;
    }
    {
        float4 v = *(const float4*)(kbf + ((size_t)bh*S_LEN + kr_s)*HD + kc_s*8);
        *(float4*)(Ks + ((size_t)kr_s*12 + (kc_s ^ ((kr_s >> 1) & 3)))*8) = v;
        if (tid < 256) {
            float4 v2 = *(const float4*)(kbf + ((size_t)bh*S_LEN + kr2_s)*HD + kc2_s*8);
            *(float4*)(Ks + ((size_t)kr2_s*12 + (kc2_s ^ ((kr2_s >> 1) & 3)))*8) = v2;
        }
    }
    __syncthreads();
    bf16x8 qf[3];
    #pragma unroll
    for (int kk = 0; kk < 3; ++kk) {
        int r = rt*16 + lh;
        qf[kk] = *(const bf16x8*)(Qtmp + ((size_t)r*12 + ((kk*4+g) ^ ((r >> 1) & 3)))*8);
    }
    __syncthreads();

    const float DW = *pdw, AW = *paw, CB = *pdb + *pab;
    const int trow = tid >> 4, c4 = tid & 15;
    const size_t drow = ((size_t)b*S_LEN + q0 + trow)*S_LEN;

    float lpart = 0.f;

    for (int kt = 0; kt < 32; ++kt) {
        int coff = kt*64 + c4*4;
        float4 kreg0, kreg1;
        if (kt < 31) {
            kreg0 = *(const float4*)(kbf + ((size_t)bh*S_LEN + (kt+1)*64 + kr_s)*HD + kc_s*8);
            if (tid < 256)
                kreg1 = *(const float4*)(kbf + ((size_t)bh*S_LEN + (kt+1)*64 + kr2_s)*HD + kc2_s*8);
        }
        float4 d4 = *(const float4*)(dist + drow + coff);
        float4 g4 = *(const float4*)(ang  + drow + coff);
        float4 m4 = *(const float4*)(mask + b*S_LEN + coff);

        __builtin_amdgcn_s_setprio(1);
        f32x4 acc = (f32x4){0.f,0.f,0.f,0.f};
        #pragma unroll
        for (int kk = 0; kk < 3; ++kk) {
            int kr = ct*16 + lh;
            bf16x8 kf = *(const bf16x8*)(Ks + ((size_t)kr*12 + ((kk*4+g) ^ ((kr >> 1) & 3)))*8);
            acc = MFMA16(qf[kk], kf, acc);
        }
        __builtin_amdgcn_s_setprio(0);
        #pragma unroll
        for (int r = 0; r < 4; ++r)
            Sf[(rt*16 + g*4 + r)*68 + ct*16 + lh] = acc[r];
        __syncthreads();   // B2

        if (kt < 31) {
            *(float4*)(Ks + ((size_t)kr_s*12 + (kc_s ^ ((kr_s >> 1) & 3)))*8) = kreg0;
            if (tid < 256)
                *(float4*)(Ks + ((size_t)kr2_s*12 + (kc2_s ^ ((kr2_s >> 1) & 3)))*8) = kreg1;
        }
        float4 s4 = *(const float4*)&Sf[trow*68 + c4*4];
        float e0 = __expf(s4.x*RSQRT_D + DW*d4.x + AW*g4.x + CB + (1.f - m4.x) * -10000.f);
        float e1 = __expf(s4.y*RSQRT_D + DW*d4.y + AW*g4.y + CB + (1.f - m4.y) * -10000.f);
        float e2 = __expf(s4.z*RSQRT_D + DW*d4.z + AW*g4.z + CB + (1.f - m4.z) * -10000.f);
        float e3 = __expf(s4.w*RSQRT_D + DW*d4.w + AW*g4.w + CB + (1.f - m4.w) * -10000.f);
        lpart += (e0 + e1) + (e2 + e3);
        __syncthreads();   // B1
    }

    #pragma unroll
    for (int off = 1; off <= 8; off <<= 1) lpart += __shfl_xor(lpart, off);
    if (c4 == 0) lrow[(bh << 11) + q0 + trow] = lpart;
}

// ---------------------------------------------------------------------------
// Pass 2: fused QK^T recompute + probs + PV, with the same T1 XCD swizzle.
// grid 1024 flat, 512 thr, 3 barriers/iter.
// ---------------------------------------------------------------------------
__global__ __launch_bounds__(512) void attn_pv_kernel(
    const u16* __restrict__ qbf, const u16* __restrict__ kbf,
    const u16* __restrict__ vt,
    const float* __restrict__ dist, const float* __restrict__ ang,
    const float* __restrict__ mask,
    const float* __restrict__ pdw, const float* __restrict__ pdb,
    const float* __restrict__ paw, const float* __restrict__ pab,
    const float* __restrict__ lrow,
    float* __restrict__ probs, u16* __restrict__ ctxb)
{
    const int flat = blockIdx.y * 64 + blockIdx.x;
    const int xcd = flat & 7, jj = flat >> 3;
    const int bh = xcd*2 + (jj >> 6);
    const int q0 = (jj & 63) * 32;
    const int b = bh >> 3, h = bh & 7;
    const int tid = threadIdx.x;
    const int lane = tid & 63, w = tid >> 6, lh = lane & 15, g = lane >> 4;
    const int rt = w >> 2;
    const int ct = w & 3;

    __shared__ __align__(16) u16 Ks[64*96];      // 12 KB
    __shared__ __align__(16) u16 Vs[96*64];      // 12 KB
    __shared__ __align__(16) float Sf[32*68];    // 8.5 KB (Qtmp in prologue)
    __shared__ __align__(16) u16 Ps[32*64];      // 4 KB

    const int kr_s = tid / 12, kc_s = tid - (tid / 12) * 12;
    const int kr2_s = (tid + 512) / 12, kc2_s = (tid + 512) - ((tid + 512) / 12) * 12;
    const int vr_s = tid >> 3, vc_s = tid & 7;
    const int vr2_s = (tid + 512) >> 3, vc2_s = (tid + 512) & 7;

    // prologue: stage Q (Sf region), K0, V0
    u16* Qtmp = (u16*)Sf;
    if (tid < 384) {
        int r = tid / 12, c = tid % 12;
        float4 v = *(const float4*)(qbf + ((size_t)bh*S_LEN + q0 + r)*HD + c*8);
        *(float4*)(Qtmp + ((size_t)r*12 + (c ^ ((r >> 1) & 3)))*8) = v;
    }
    {
        float4 v = *(const float4*)(kbf + ((size_t)bh*S_LEN + kr_s)*HD + kc_s*8);
        *(float4*)(Ks + ((size_t)kr_s*12 + (kc_s ^ ((kr_s >> 1) & 3)))*8) = v;
        if (tid < 256) {
            float4 v2 = *(const float4*)(kbf + ((size_t)bh*S_LEN + kr2_s)*HD + kc2_s*8);
            *(float4*)(Ks + ((size_t)kr2_s*12 + (kc2_s ^ ((kr2_s >> 1) & 3)))*8) = v2;
        }
        float4 v4 = *(const float4*)(vt + ((size_t)bh*HD + vr_s)*S_LEN + vc_s*8);
        *(float4*)(Vs + ((size_t)vr_s*8 + (vc_s ^ (vr_s & 7)))*8) = v4;
        if (tid < 256) {
            float4 v42 = *(const float4*)(vt + ((size_t)bh*HD + vr2_s)*S_LEN + vc2_s*8);
            *(float4*)(Vs + ((size_t)vr2_s*8 + (vc2_s ^ (vr2_s & 7)))*8) = v42;
        }
    }
    __syncthreads();
    bf16x8 qf[3];
    #pragma unroll
    for (int kk = 0; kk < 3; ++kk) {
        int r = rt*16 + lh;
        qf[kk] = *(const bf16x8*)(Qtmp + ((size_t)r*12 + ((kk*4+g) ^ ((r >> 1) & 3)))*8);
    }
    __syncthreads();   // release Qtmp before Sf f32 use

    const float DW = *pdw, AW = *paw, CB = *pdb + *pab;
    const int trow = tid >> 4, c4 = tid & 15;
    const size_t drow = ((size_t)b*S_LEN + q0 + trow)*S_LEN;
    const int uoffP = (trow*8 + ((c4 >> 1) ^ (trow & 7)))*8 + (c4 & 1)*4;
    const float invl_row = 1.0f / lrow[(bh << 11) + q0 + trow];

    const int dt1 = ct;
    const bool two = (ct < 2);
    const int dt2 = ct + 4;
    const int prowPV = rt*16 + lh;
    f32x4 accA = (f32x4){0.f,0.f,0.f,0.f};
    f32x4 accB = (f32x4){0.f,0.f,0.f,0.f};

    for (int kt = 0; kt < 32; ++kt) {
        int coff = kt*64 + c4*4;
        // prefetch next K/V into regs (consumed after B2 / after B1)
        float4 kp0, kp1, vp0, vp1;
        if (kt < 31) {
            kp0 = *(const float4*)(kbf + ((size_t)bh*S_LEN + (kt+1)*64 + kr_s)*HD + kc_s*8);
            if (tid < 256)
                kp1 = *(const float4*)(kbf + ((size_t)bh*S_LEN + (kt+1)*64 + kr2_s)*HD + kc2_s*8);
            vp0 = *(const float4*)(vt + ((size_t)bh*HD + vr_s)*S_LEN + (kt+1)*64 + vc_s*8);
            if (tid < 256)
                vp1 = *(const float4*)(vt + ((size_t)bh*HD + vr2_s)*S_LEN + (kt+1)*64 + vc2_s*8);
        }
        float4 d4 = *(const float4*)(dist + drow + coff);
        float4 g4 = *(const float4*)(ang  + drow + coff);
        float4 m4 = *(const float4*)(mask + b*S_LEN + coff);

        // QK MFMA
        __builtin_amdgcn_s_setprio(1);
        f32x4 acc = (f32x4){0.f,0.f,0.f,0.f};
        #pragma unroll
        for (int kk = 0; kk < 3; ++kk) {
            int kr = ct*16 + lh;
            bf16x8 kf = *(const bf16x8*)(Ks + ((size_t)kr*12 + ((kk*4+g) ^ ((kr >> 1) & 3)))*8);
            acc = MFMA16(qf[kk], kf, acc);
        }
        __builtin_amdgcn_s_setprio(0);
        #pragma unroll
        for (int r = 0; r < 4; ++r)
            Sf[(rt*16 + g*4 + r)*68 + ct*16 + lh] = acc[r];
        __syncthreads();   // B2: Sf ready, Ks reads done

        // ds_write next K (Ks reads complete)
        if (kt < 31) {
            *(float4*)(Ks + ((size_t)kr_s*12 + (kc_s ^ ((kr_s >> 1) & 3)))*8) = kp0;
            if (tid < 256)
                *(float4*)(Ks + ((size_t)kr2_s*12 + (kc2_s ^ ((kr2_s >> 1) & 3)))*8) = kp1;
        }
        // epilogue: u = exp(s); probs = u*invl; Ps = u (bf16)
        {
            float4 s4 = *(const float4*)&Sf[trow*68 + c4*4];
            float e0 = __expf(s4.x*RSQRT_D + DW*d4.x + AW*g4.x + CB + (1.f - m4.x) * -10000.f);
            float e1 = __expf(s4.y*RSQRT_D + DW*d4.y + AW*g4.y + CB + (1.f - m4.y) * -10000.f);
            float e2 = __expf(s4.z*RSQRT_D + DW*d4.z + AW*g4.z + CB + (1.f - m4.z) * -10000.f);
            float e3 = __expf(s4.w*RSQRT_D + DW*d4.w + AW*g4.w + CB + (1.f - m4.w) * -10000.f);
            float4 p;
            p.x = e0*invl_row; p.y = e1*invl_row; p.z = e2*invl_row; p.w = e3*invl_row;
            *(float4*)(probs + ((size_t)bh*S_LEN + q0 + trow)*S_LEN + coff) = p;
            U16x4 uk;
            uk.u[0] = f2bf(e0); uk.u[1] = f2bf(e1); uk.u[2] = f2bf(e2); uk.u[3] = f2bf(e3);
            *(uint2*)(Ps + uoffP) = uk.v2;
        }
        __syncthreads();   // B3: Ps ready (and Ks[kt+1] ready)

        // PV MFMA (Ps x Vs[kt])
        bf16x8 pa[2];
        #pragma unroll
        for (int kk = 0; kk < 2; ++kk)
            pa[kk] = *(const bf16x8*)(Ps + ((size_t)prowPV*8 + ((kk*4+g) ^ (prowPV & 7)))*8);
        __builtin_amdgcn_s_setprio(1);
        #pragma unroll
        for (int kk = 0; kk < 2; ++kk) {
            int vr = dt1*16 + lh;
            bf16x8 vf = *(const bf16x8*)(Vs + ((size_t)vr*8 + ((kk*4+g) ^ (vr & 7)))*8);
            accA = MFMA16(pa[kk], vf, accA);
        }
        if (two) {
            #pragma unroll
            for (int kk = 0; kk < 2; ++kk) {
                int vr = dt2*16 + lh;
                bf16x8 vf = *(const bf16x8*)(Vs + ((size_t)vr*8 + ((kk*4+g) ^ (vr & 7)))*8);
                accB = MFMA16(pa[kk], vf, accB);
            }
        }
        __builtin_amdgcn_s_setprio(0);
        __syncthreads();   // B1: Vs/Ps reads done

        // ds_write next V (ordered vs next PV reads by next iter's B2+B3)
        if (kt < 31) {
            *(float4*)(Vs + ((size_t)vr_s*8 + (vc_s ^ (vr_s & 7)))*8) = vp0;
            if (tid < 256)
                *(float4*)(Vs + ((size_t)vr2_s*8 + (vc2_s ^ (vr2_s & 7)))*8) = vp1;
        }
    }

    // ctx write (scaled by 1/l per row)
    float ils[4];
    #pragma unroll
    for (int r = 0; r < 4; ++r)
        ils[r] = 1.0f / lrow[(bh << 11) + q0 + rt*16 + g*4 + r];
    #pragma unroll
    for (int r = 0; r < 4; ++r) {
        int qrow = q0 + rt*16 + g*4 + r;
        ctxb[((size_t)(b*S_LEN + qrow))*EMB + h*HD + dt1*16 + lh] = f2bf(accA[r] * ils[r]);
        if (two)
            ctxb[((size_t)(b*S_LEN + qrow))*EMB + h*HD + dt2*16 + lh] = f2bf(accB[r] * ils[r]);
    }
}

// ---------------------------------------------------------------------------
// Output proj MFMA (64x64 tile)
// ---------------------------------------------------------------------------
__global__ __launch_bounds__(256) void out_mfma_kernel(
    const u16* __restrict__ ctxb, const u16* __restrict__ WoT,
    const float* __restrict__ bo, const float* __restrict__ hs,
    float* __restrict__ res)
{
    __shared__ __align__(16) u16 As[64*64];
    __shared__ __align__(16) u16 Bs[64*64];
    const int tid = threadIdx.x;
    const int w = tid >> 6, lane = tid & 63, lh = lane & 15, g = lane >> 4;
    const int wm = w >> 1, wn = w & 1;
    const int row0 = blockIdx.y * 64, col0 = blockIdx.x * 64;

    f32x4 acc[2][2];
    #pragma unroll
    for (int i = 0; i < 2; ++i)
        #pragma unroll
        for (int j = 0; j < 2; ++j) acc[i][j] = (f32x4){0.f,0.f,0.f,0.f};

    for (int k0 = 0; k0 < EMB; k0 += 64) {
        __syncthreads();
        #pragma unroll
        for (int i = 0; i < 2; ++i) {
            int idx = tid + 256*i;
            int r = idx >> 3, c = idx & 7;
            float4 a4 = *(const float4*)(ctxb + (size_t)(row0 + r)*EMB + k0 + c*8);
            *(float4*)(As + ((size_t)r*8 + (c ^ (r & 7)))*8) = a4;
            float4 b4 = *(const float4*)(WoT + (size_t)(col0 + r)*EMB + k0 + c*8);
            *(float4*)(Bs + ((size_t)r*8 + (c ^ (r & 7)))*8) = b4;
        }
        __syncthreads();
        bf16x8 af[2][2], bfr[2][2];
        #pragma unroll
        for (int mt = 0; mt < 2; ++mt)
            #pragma unroll
            for (int kk = 0; kk < 2; ++kk) {
                int r = wm*32 + mt*16 + lh;
                af[mt][kk] = *(const bf16x8*)(As + ((size_t)r*8 + ((kk*4+g) ^ (lh & 7)))*8);
            }
        #pragma unroll
        for (int nt = 0; nt < 2; ++nt)
            #pragma unroll
            for (int kk = 0; kk < 2; ++kk) {
                int r = wn*32 + nt*16 + lh;
                bfr[nt][kk] = *(const bf16x8*)(Bs + ((size_t)r*8 + ((kk*4+g) ^ (lh & 7)))*8);
            }
        #pragma unroll
        for (int mt = 0; mt < 2; ++mt)
            #pragma unroll
            for (int nt = 0; nt < 2; ++nt)
                #pragma unroll
                for (int kk = 0; kk < 2; ++kk)
                    acc[mt][nt] = MFMA16(af[mt][kk], bfr[nt][kk], acc[mt][nt]);
    }

    #pragma unroll
    for (int mt = 0; mt < 2; ++mt)
        #pragma unroll
        for (int nt = 0; nt < 2; ++nt)
            #pragma unroll
            for (int r = 0; r < 4; ++r) {
                int tt = row0 + wm*32 + mt*16 + g*4 + r;
                int o  = col0 + wn*32 + nt*16 + lh;
                res[(size_t)tt*EMB + o] = acc[mt][nt][r] + bo[o] + hs[(size_t)tt*EMB + o];
            }
}

// ---------------------------------------------------------------------------
// LayerNorm in place over last dim 768. grid NTOK, block 256.
// ---------------------------------------------------------------------------
__device__ __forceinline__ float block_sum256(float v, float* red) {
    #pragma unroll
    for (int off = 32; off > 0; off >>= 1) v += __shfl_down(v, off);
    int lane = threadIdx.x & 63, w = threadIdx.x >> 6;
    __syncthreads();
    if (lane == 0) red[w] = v;
    __syncthreads();
    return red[0] + red[1] + red[2] + red[3];
}

__global__ __launch_bounds__(256) void ln_kernel(
    float* __restrict__ res, const float* __restrict__ gamma, const float* __restrict__ beta)
{
    const int t = blockIdx.x;
    float* row = res + (size_t)t * EMB;
    const int tid = threadIdx.x;
    __shared__ float red[4];

    float x0 = row[tid], x1 = row[tid + 256], x2 = row[tid + 512];
    float s = block_sum256(x0 + x1 + x2, red);
    float mu = s * (1.0f / (float)EMB);
    float d0 = x0 - mu, d1 = x1 - mu, d2 = x2 - mu;
    float sq = block_sum256(d0*d0 + d1*d1 + d2*d2, red);
    float var = sq * (1.0f / (float)EMB);
    float scale = rsqrtf(var + 1e-5f);

    row[tid]       = d0 * scale * gamma[tid]       + beta[tid];
    row[tid + 256] = d1 * scale * gamma[tid + 256] + beta[tid + 256];
    row[tid + 512] = d2 * scale * gamma[tid + 512] + beta[tid + 512];
}

// ---------------------------------------------------------------------------
extern "C" void kernel_launch(void* const* d_in, const int* in_sizes, int n_in,
                              void* d_out, int out_size, void* d_ws, size_t ws_size,
                              hipStream_t stream)
{
    (void)in_sizes; (void)n_in; (void)out_size; (void)ws_size;

    const float* hs   = (const float*)d_in[0];
    const float* dist = (const float*)d_in[1];
    const float* ang  = (const float*)d_in[2];
    const float* mask = (const float*)d_in[3];
    const float* Wq = (const float*)d_in[4];  const float* bq = (const float*)d_in[5];
    const float* Wk = (const float*)d_in[6];  const float* bk = (const float*)d_in[7];
    const float* Wv = (const float*)d_in[8];  const float* bv = (const float*)d_in[9];
    const float* dw = (const float*)d_in[10]; const float* db = (const float*)d_in[11];
    const float* aw = (const float*)d_in[12]; const float* ab = (const float*)d_in[13];
    const float* Wo = (const float*)d_in[14]; const float* bo = (const float*)d_in[15];
    const float* gamma = (const float*)d_in[16]; const float* beta = (const float*)d_in[17];

    float* out   = (float*)d_out;                      // [B,S,E]
    float* probs = out + (size_t)NTOK * EMB;           // [B,H,S,S]

    u16* hsb = (u16*)d_ws;
    u16* WqT = hsb + (size_t)NTOK*EMB;
    u16* WkT = WqT + (size_t)EMB*EMB;
    u16* WvT = WkT + (size_t)EMB*EMB;
    u16* WoT = WvT + (size_t)EMB*EMB;
    u16* qb  = WoT + (size_t)EMB*EMB;
    u16* kb  = qb + (size_t)NTOK*EMB;
    u16* vb  = kb + (size_t)NTOK*EMB;
    u16* vtb = vb + (size_t)NTOK*EMB;
    u16* ctxb = qb;                                    // reuse q region after attn
    float* lrow = (float*)(vtb + (size_t)NTOK*EMB);

    cvt_bf16_kernel<<<dim3(NTOK*EMB/4/256), dim3(256), 0, stream>>>(hs, hsb, NTOK*EMB/4);
    transcvt4_kernel<<<dim3(12,12,4), dim3(256), 0, stream>>>(
        Wq, WqT, Wk, WkT, Wv, WvT, Wo, WoT);

    qkv_mfma_kernel<<<dim3(EMB/64, NTOK/64, 3), dim3(256), 0, stream>>>(
        hsb, WqT, bq, WkT, bk, WvT, bv, qb, kb, vb);

    vtrans_kernel<<<dim3(S_LEN/64, BATCH*NH), dim3(256), 0, stream>>>(vb, vtb);

    scores_l_kernel<<<dim3(S_LEN/32, BATCH*NH), dim3(512), 0, stream>>>(
        qb, kb, dist, ang, mask, dw, db, aw, ab, lrow);

    attn_pv_kernel<<<dim3(S_LEN/32, BATCH*NH), dim3(512), 0, stream>>>(
        qb, kb, vtb, dist, ang, mask, dw, db, aw, ab, lrow, probs, ctxb);

    out_mfma_kernel<<<dim3(EMB/64, NTOK/64), dim3(256), 0, stream>>>(
        ctxb, WoT, bo, hs, out);

    ln_kernel<<<dim3(NTOK), dim3(256), 0, stream>>>(out, gamma, beta);
}

// Round 23
// 229.938 us; speedup vs baseline: 1.1950x; 1.1950x over previous
//
#include <hip/hip_runtime.h>
#include <math.h>

#define S_LEN 2048
#define BATCH 2
#define EMB 768
#define NH 8
#define HD 96
#define NTOK (BATCH*S_LEN)
#define RSQRT_D 0.10206207261596575f   // 1/sqrt(96)

typedef unsigned short u16;
typedef __attribute__((ext_vector_type(8))) short bf16x8;
typedef __attribute__((ext_vector_type(4))) float f32x4;

#define MFMA16(a,b,c) __builtin_amdgcn_mfma_f32_16x16x32_bf16(a,b,c,0,0,0)

__device__ __forceinline__ u16 f2bf(float f){
    unsigned u = __float_as_uint(f);
    return (u16)((u + 0x7fffu + ((u>>16)&1u)) >> 16);
}
__device__ __forceinline__ float bf2f(unsigned u){
    return __uint_as_float(u << 16);
}

union U16x8 { u16 u[8]; float4 f4; };
union U16x4 { u16 u[4]; uint2 v2; };

// ---------------------------------------------------------------------------
// f32 -> bf16 elementwise convert (vectorized x4)
// ---------------------------------------------------------------------------
__global__ __launch_bounds__(256) void cvt_bf16_kernel(
    const float* __restrict__ src, u16* __restrict__ dst, int n4)
{
    int i = blockIdx.x * 256 + threadIdx.x;
    if (i < n4) {
        float4 v = ((const float4*)src)[i];
        U16x4 o;
        o.u[0] = f2bf(v.x); o.u[1] = f2bf(v.y); o.u[2] = f2bf(v.z); o.u[3] = f2bf(v.w);
        *(uint2*)(dst + (size_t)i*4) = o.v2;
    }
}

// ---------------------------------------------------------------------------
// 4x W[768][768] f32 -> Wt[n][k] bf16 (transpose + convert), one launch.
// grid (12,12,4), 256 thr; blockIdx.z selects the weight matrix.
// ---------------------------------------------------------------------------
__global__ __launch_bounds__(256) void transcvt4_kernel(
    const float* __restrict__ W0, u16* __restrict__ T0,
    const float* __restrict__ W1, u16* __restrict__ T1,
    const float* __restrict__ W2, u16* __restrict__ T2,
    const float* __restrict__ W3, u16* __restrict__ T3)
{
    const float* W; u16* Wt;
    switch (blockIdx.z) {
        case 0:  W = W0; Wt = T0; break;
        case 1:  W = W1; Wt = T1; break;
        case 2:  W = W2; Wt = T2; break;
        default: W = W3; Wt = T3; break;
    }
    __shared__ float T[64][65];
    const int t = threadIdx.x;
    const int k0 = blockIdx.y * 64, n0 = blockIdx.x * 64;
    #pragma unroll
    for (int i = 0; i < 4; ++i) {
        int idx = t + 256*i;
        int r = idx >> 4, c4 = idx & 15;
        float4 v = *(const float4*)(W + (size_t)(k0 + r)*EMB + n0 + c4*4);
        T[r][c4*4+0] = v.x; T[r][c4*4+1] = v.y; T[r][c4*4+2] = v.z; T[r][c4*4+3] = v.w;
    }
    __syncthreads();
    #pragma unroll
    for (int i = 0; i < 2; ++i) {
        int idx = t + 256*i;
        int n = idx >> 3, c = idx & 7;
        U16x8 o;
        #pragma unroll
        for (int e = 0; e < 8; ++e) o.u[e] = f2bf(T[c*8+e][n]);
        *(float4*)(Wt + (size_t)(n0 + n)*EMB + k0 + c*8) = o.f4;
    }
}

// ---------------------------------------------------------------------------
// QKV projection MFMA (64x64 tile — empirically best at K=768)
// ---------------------------------------------------------------------------
__global__ __launch_bounds__(256) void qkv_mfma_kernel(
    const u16* __restrict__ hsb,
    const u16* __restrict__ WqT, const float* __restrict__ bq,
    const u16* __restrict__ WkT, const float* __restrict__ bk,
    const u16* __restrict__ WvT, const float* __restrict__ bv,
    u16* __restrict__ qo, u16* __restrict__ ko, u16* __restrict__ vo)
{
    const u16* Wt; const float* bias; u16* out;
    if (blockIdx.z == 0)      { Wt = WqT; bias = bq; out = qo; }
    else if (blockIdx.z == 1) { Wt = WkT; bias = bk; out = ko; }
    else                      { Wt = WvT; bias = bv; out = vo; }

    __shared__ __align__(16) u16 As[64*64];
    __shared__ __align__(16) u16 Bs[64*64];
    const int tid = threadIdx.x;
    const int w = tid >> 6, lane = tid & 63, lh = lane & 15, g = lane >> 4;
    const int wm = w >> 1, wn = w & 1;
    const int row0 = blockIdx.y * 64, col0 = blockIdx.x * 64;

    f32x4 acc[2][2];
    #pragma unroll
    for (int i = 0; i < 2; ++i)
        #pragma unroll
        for (int j = 0; j < 2; ++j) acc[i][j] = (f32x4){0.f,0.f,0.f,0.f};

    for (int k0 = 0; k0 < EMB; k0 += 64) {
        __syncthreads();
        #pragma unroll
        for (int i = 0; i < 2; ++i) {
            int idx = tid + 256*i;
            int r = idx >> 3, c = idx & 7;
            float4 a4 = *(const float4*)(hsb + (size_t)(row0 + r)*EMB + k0 + c*8);
            *(float4*)(As + ((size_t)r*8 + (c ^ (r & 7)))*8) = a4;
            float4 b4 = *(const float4*)(Wt + (size_t)(col0 + r)*EMB + k0 + c*8);
            *(float4*)(Bs + ((size_t)r*8 + (c ^ (r & 7)))*8) = b4;
        }
        __syncthreads();
        bf16x8 af[2][2], bfr[2][2];
        #pragma unroll
        for (int mt = 0; mt < 2; ++mt)
            #pragma unroll
            for (int kk = 0; kk < 2; ++kk) {
                int r = wm*32 + mt*16 + lh;
                af[mt][kk] = *(const bf16x8*)(As + ((size_t)r*8 + ((kk*4+g) ^ (lh & 7)))*8);
            }
        #pragma unroll
        for (int nt = 0; nt < 2; ++nt)
            #pragma unroll
            for (int kk = 0; kk < 2; ++kk) {
                int r = wn*32 + nt*16 + lh;
                bfr[nt][kk] = *(const bf16x8*)(Bs + ((size_t)r*8 + ((kk*4+g) ^ (lh & 7)))*8);
            }
        #pragma unroll
        for (int mt = 0; mt < 2; ++mt)
            #pragma unroll
            for (int nt = 0; nt < 2; ++nt)
                #pragma unroll
                for (int kk = 0; kk < 2; ++kk)
                    acc[mt][nt] = MFMA16(af[mt][kk], bfr[nt][kk], acc[mt][nt]);
    }

    #pragma unroll
    for (int mt = 0; mt < 2; ++mt)
        #pragma unroll
        for (int nt = 0; nt < 2; ++nt)
            #pragma unroll
            for (int r = 0; r < 4; ++r) {
                int tt = row0 + wm*32 + mt*16 + g*4 + r;
                int o  = col0 + wn*32 + nt*16 + lh;
                float val = acc[mt][nt][r] + bias[o];
                int b = tt >> 11, s = tt & (S_LEN - 1);
                int h = o / HD, d = o - h*HD;
                out[((size_t)(b*NH + h)*S_LEN + s)*HD + d] = f2bf(val);
            }
}

// ---------------------------------------------------------------------------
// V transpose: vb[B,H,S,D] bf16 -> vt[B,H,D,S] bf16
// ---------------------------------------------------------------------------
__global__ __launch_bounds__(256) void vtrans_kernel(
    const u16* __restrict__ vb, u16* __restrict__ vt)
{
    const int bh = blockIdx.y;
    const int s0 = blockIdx.x * 64;
    __shared__ __align__(16) u16 T[64*96];
    const int t = threadIdx.x;
    #pragma unroll
    for (int i = 0; i < 3; ++i) {
        int idx = t + 256*i;
        int s = idx / 12, c = idx % 12;
        float4 v = *(const float4*)(vb + ((size_t)bh*S_LEN + s0 + s)*HD + c*8);
        *(float4*)(T + ((size_t)s*12 + c)*8) = v;
    }
    __syncthreads();
    #pragma unroll
    for (int i = 0; i < 3; ++i) {
        int idx = t + 256*i;
        int d = idx >> 3, c = idx & 7;
        U16x8 o;
        #pragma unroll
        for (int e = 0; e < 8; ++e) o.u[e] = T[(size_t)(c*8+e)*HD + d];
        *(float4*)(vt + ((size_t)bh*HD + d)*S_LEN + s0 + c*8) = o.f4;
    }
}

// ---------------------------------------------------------------------------
// Pass 1: l-only scores. QK^T + coalesced epilogue, NO u store — tiny LDS
// (21 KB) -> high occupancy. Writes lrow (raw sum). grid (64,16), 512 thr.
// ---------------------------------------------------------------------------
__global__ __launch_bounds__(512) void scores_l_kernel(
    const u16* __restrict__ qbf, const u16* __restrict__ kbf,
    const float* __restrict__ dist, const float* __restrict__ ang,
    const float* __restrict__ mask,
    const float* __restrict__ pdw, const float* __restrict__ pdb,
    const float* __restrict__ paw, const float* __restrict__ pab,
    float* __restrict__ lrow)
{
    const int bh = blockIdx.y, b = bh >> 3;
    const int q0 = blockIdx.x * 32;
    const int tid = threadIdx.x;
    const int lane = tid & 63, w = tid >> 6, lh = lane & 15, g = lane >> 4;
    const int rt = w >> 2;
    const int ct = w & 3;

    __shared__ __align__(16) u16 Ks[64*96];
    __shared__ __align__(16) float Sf[32*68];

    const int kr_s = tid / 12, kc_s = tid - (tid / 12) * 12;
    const int kr2_s = (tid + 512) / 12, kc2_s = (tid + 512) - ((tid + 512) / 12) * 12;

    // prologue: stage Q (Sf region) + K0
    u16* Qtmp = (u16*)Sf;
    if (tid < 384) {
        int r = tid / 12, c = tid % 12;
        float4 v = *(const float4*)(qbf + ((size_t)bh*S_LEN + q0 + r)*HD + c*8);
        *(float4*)(Qtmp + ((size_t)r*12 + (c ^ ((r >> 1) & 3)))*8) = v;
    }
    {
        float4 v = *(const float4*)(kbf + ((size_t)bh*S_LEN + kr_s)*HD + kc_s*8);
        *(float4*)(Ks + ((size_t)kr_s*12 + (kc_s ^ ((kr_s >> 1) & 3)))*8) = v;
        if (tid < 256) {
            float4 v2 = *(const float4*)(kbf + ((size_t)bh*S_LEN + kr2_s)*HD + kc2_s*8);
            *(float4*)(Ks + ((size_t)kr2_s*12 + (kc2_s ^ ((kr2_s >> 1) & 3)))*8) = v2;
        }
    }
    __syncthreads();
    bf16x8 qf[3];
    #pragma unroll
    for (int kk = 0; kk < 3; ++kk) {
        int r = rt*16 + lh;
        qf[kk] = *(const bf16x8*)(Qtmp + ((size_t)r*12 + ((kk*4+g) ^ ((r >> 1) & 3)))*8);
    }
    __syncthreads();

    const float DW = *pdw, AW = *paw, CB = *pdb + *pab;
    const int trow = tid >> 4, c4 = tid & 15;
    const size_t drow = ((size_t)b*S_LEN + q0 + trow)*S_LEN;

    float lpart = 0.f;

    for (int kt = 0; kt < 32; ++kt) {
        int coff = kt*64 + c4*4;
        float4 kreg0, kreg1;
        if (kt < 31) {
            kreg0 = *(const float4*)(kbf + ((size_t)bh*S_LEN + (kt+1)*64 + kr_s)*HD + kc_s*8);
            if (tid < 256)
                kreg1 = *(const float4*)(kbf + ((size_t)bh*S_LEN + (kt+1)*64 + kr2_s)*HD + kc2_s*8);
        }
        float4 d4 = *(const float4*)(dist + drow + coff);
        float4 g4 = *(const float4*)(ang  + drow + coff);
        float4 m4 = *(const float4*)(mask + b*S_LEN + coff);

        __builtin_amdgcn_s_setprio(1);
        f32x4 acc = (f32x4){0.f,0.f,0.f,0.f};
        #pragma unroll
        for (int kk = 0; kk < 3; ++kk) {
            int kr = ct*16 + lh;
            bf16x8 kf = *(const bf16x8*)(Ks + ((size_t)kr*12 + ((kk*4+g) ^ ((kr >> 1) & 3)))*8);
            acc = MFMA16(qf[kk], kf, acc);
        }
        __builtin_amdgcn_s_setprio(0);
        #pragma unroll
        for (int r = 0; r < 4; ++r)
            Sf[(rt*16 + g*4 + r)*68 + ct*16 + lh] = acc[r];
        __syncthreads();   // B2

        if (kt < 31) {
            *(float4*)(Ks + ((size_t)kr_s*12 + (kc_s ^ ((kr_s >> 1) & 3)))*8) = kreg0;
            if (tid < 256)
                *(float4*)(Ks + ((size_t)kr2_s*12 + (kc2_s ^ ((kr2_s >> 1) & 3)))*8) = kreg1;
        }
        float4 s4 = *(const float4*)&Sf[trow*68 + c4*4];
        float e0 = __expf(s4.x*RSQRT_D + DW*d4.x + AW*g4.x + CB + (1.f - m4.x) * -10000.f);
        float e1 = __expf(s4.y*RSQRT_D + DW*d4.y + AW*g4.y + CB + (1.f - m4.y) * -10000.f);
        float e2 = __expf(s4.z*RSQRT_D + DW*d4.z + AW*g4.z + CB + (1.f - m4.z) * -10000.f);
        float e3 = __expf(s4.w*RSQRT_D + DW*d4.w + AW*g4.w + CB + (1.f - m4.w) * -10000.f);
        lpart += (e0 + e1) + (e2 + e3);
        __syncthreads();   // B1
    }

    #pragma unroll
    for (int off = 1; off <= 8; off <<= 1) lpart += __shfl_xor(lpart, off);
    if (c4 == 0) lrow[(bh << 11) + q0 + trow] = lpart;
}

// ---------------------------------------------------------------------------
// Pass 2: fused QK^T recompute + probs write (normalized, invl from pass 1)
// + PV. No Us stripe -> 37 KB LDS -> 4 blocks/CU (16 waves/CU).
// grid (64,16), 512 thr, 3 barriers/iter.
// ---------------------------------------------------------------------------
__global__ __launch_bounds__(512) void attn_pv_kernel(
    const u16* __restrict__ qbf, const u16* __restrict__ kbf,
    const u16* __restrict__ vt,
    const float* __restrict__ dist, const float* __restrict__ ang,
    const float* __restrict__ mask,
    const float* __restrict__ pdw, const float* __restrict__ pdb,
    const float* __restrict__ paw, const float* __restrict__ pab,
    const float* __restrict__ lrow,
    float* __restrict__ probs, u16* __restrict__ ctxb)
{
    const int bh = blockIdx.y, b = bh >> 3, h = bh & 7;
    const int q0 = blockIdx.x * 32;
    const int tid = threadIdx.x;
    const int lane = tid & 63, w = tid >> 6, lh = lane & 15, g = lane >> 4;
    const int rt = w >> 2;
    const int ct = w & 3;

    __shared__ __align__(16) u16 Ks[64*96];      // 12 KB
    __shared__ __align__(16) u16 Vs[96*64];      // 12 KB
    __shared__ __align__(16) float Sf[32*68];    // 8.5 KB (Qtmp in prologue)
    __shared__ __align__(16) u16 Ps[32*64];      // 4 KB

    const int kr_s = tid / 12, kc_s = tid - (tid / 12) * 12;
    const int kr2_s = (tid + 512) / 12, kc2_s = (tid + 512) - ((tid + 512) / 12) * 12;
    const int vr_s = tid >> 3, vc_s = tid & 7;
    const int vr2_s = (tid + 512) >> 3, vc2_s = (tid + 512) & 7;

    // prologue: stage Q (Sf region), K0, V0
    u16* Qtmp = (u16*)Sf;
    if (tid < 384) {
        int r = tid / 12, c = tid % 12;
        float4 v = *(const float4*)(qbf + ((size_t)bh*S_LEN + q0 + r)*HD + c*8);
        *(float4*)(Qtmp + ((size_t)r*12 + (c ^ ((r >> 1) & 3)))*8) = v;
    }
    {
        float4 v = *(const float4*)(kbf + ((size_t)bh*S_LEN + kr_s)*HD + kc_s*8);
        *(float4*)(Ks + ((size_t)kr_s*12 + (kc_s ^ ((kr_s >> 1) & 3)))*8) = v;
        if (tid < 256) {
            float4 v2 = *(const float4*)(kbf + ((size_t)bh*S_LEN + kr2_s)*HD + kc2_s*8);
            *(float4*)(Ks + ((size_t)kr2_s*12 + (kc2_s ^ ((kr2_s >> 1) & 3)))*8) = v2;
        }
        float4 v4 = *(const float4*)(vt + ((size_t)bh*HD + vr_s)*S_LEN + vc_s*8);
        *(float4*)(Vs + ((size_t)vr_s*8 + (vc_s ^ (vr_s & 7)))*8) = v4;
        if (tid < 256) {
            float4 v42 = *(const float4*)(vt + ((size_t)bh*HD + vr2_s)*S_LEN + vc2_s*8);
            *(float4*)(Vs + ((size_t)vr2_s*8 + (vc2_s ^ (vr2_s & 7)))*8) = v42;
        }
    }
    __syncthreads();
    bf16x8 qf[3];
    #pragma unroll
    for (int kk = 0; kk < 3; ++kk) {
        int r = rt*16 + lh;
        qf[kk] = *(const bf16x8*)(Qtmp + ((size_t)r*12 + ((kk*4+g) ^ ((r >> 1) & 3)))*8);
    }
    __syncthreads();   // release Qtmp before Sf f32 use

    const float DW = *pdw, AW = *paw, CB = *pdb + *pab;
    const int trow = tid >> 4, c4 = tid & 15;
    const size_t drow = ((size_t)b*S_LEN + q0 + trow)*S_LEN;
    const int uoffP = (trow*8 + ((c4 >> 1) ^ (trow & 7)))*8 + (c4 & 1)*4;
    const float invl_row = 1.0f / lrow[(bh << 11) + q0 + trow];

    const int dt1 = ct;
    const bool two = (ct < 2);
    const int dt2 = ct + 4;
    const int prowPV = rt*16 + lh;
    f32x4 accA = (f32x4){0.f,0.f,0.f,0.f};
    f32x4 accB = (f32x4){0.f,0.f,0.f,0.f};

    for (int kt = 0; kt < 32; ++kt) {
        int coff = kt*64 + c4*4;
        // prefetch next K/V into regs (consumed after B2 / after B1)
        float4 kp0, kp1, vp0, vp1;
        if (kt < 31) {
            kp0 = *(const float4*)(kbf + ((size_t)bh*S_LEN + (kt+1)*64 + kr_s)*HD + kc_s*8);
            if (tid < 256)
                kp1 = *(const float4*)(kbf + ((size_t)bh*S_LEN + (kt+1)*64 + kr2_s)*HD + kc2_s*8);
            vp0 = *(const float4*)(vt + ((size_t)bh*HD + vr_s)*S_LEN + (kt+1)*64 + vc_s*8);
            if (tid < 256)
                vp1 = *(const float4*)(vt + ((size_t)bh*HD + vr2_s)*S_LEN + (kt+1)*64 + vc2_s*8);
        }
        float4 d4 = *(const float4*)(dist + drow + coff);
        float4 g4 = *(const float4*)(ang  + drow + coff);
        float4 m4 = *(const float4*)(mask + b*S_LEN + coff);

        // QK MFMA
        __builtin_amdgcn_s_setprio(1);
        f32x4 acc = (f32x4){0.f,0.f,0.f,0.f};
        #pragma unroll
        for (int kk = 0; kk < 3; ++kk) {
            int kr = ct*16 + lh;
            bf16x8 kf = *(const bf16x8*)(Ks + ((size_t)kr*12 + ((kk*4+g) ^ ((kr >> 1) & 3)))*8);
            acc = MFMA16(qf[kk], kf, acc);
        }
        __builtin_amdgcn_s_setprio(0);
        #pragma unroll
        for (int r = 0; r < 4; ++r)
            Sf[(rt*16 + g*4 + r)*68 + ct*16 + lh] = acc[r];
        __syncthreads();   // B2: Sf ready, Ks reads done

        // ds_write next K (Ks reads complete)
        if (kt < 31) {
            *(float4*)(Ks + ((size_t)kr_s*12 + (kc_s ^ ((kr_s >> 1) & 3)))*8) = kp0;
            if (tid < 256)
                *(float4*)(Ks + ((size_t)kr2_s*12 + (kc2_s ^ ((kr2_s >> 1) & 3)))*8) = kp1;
        }
        // epilogue: u = exp(s); probs = u*invl; Ps = u (bf16)
        {
            float4 s4 = *(const float4*)&Sf[trow*68 + c4*4];
            float e0 = __expf(s4.x*RSQRT_D + DW*d4.x + AW*g4.x + CB + (1.f - m4.x) * -10000.f);
            float e1 = __expf(s4.y*RSQRT_D + DW*d4.y + AW*g4.y + CB + (1.f - m4.y) * -10000.f);
            float e2 = __expf(s4.z*RSQRT_D + DW*d4.z + AW*g4.z + CB + (1.f - m4.z) * -10000.f);
            float e3 = __expf(s4.w*RSQRT_D + DW*d4.w + AW*g4.w + CB + (1.f - m4.w) * -10000.f);
            float4 p;
            p.x = e0*invl_row; p.y = e1*invl_row; p.z = e2*invl_row; p.w = e3*invl_row;
            *(float4*)(probs + ((size_t)bh*S_LEN + q0 + trow)*S_LEN + coff) = p;
            U16x4 uk;
            uk.u[0] = f2bf(e0); uk.u[1] = f2bf(e1); uk.u[2] = f2bf(e2); uk.u[3] = f2bf(e3);
            *(uint2*)(Ps + uoffP) = uk.v2;
        }
        __syncthreads();   // B3: Ps ready (and Ks[kt+1] ready)

        // PV MFMA (Ps x Vs[kt])
        bf16x8 pa[2];
        #pragma unroll
        for (int kk = 0; kk < 2; ++kk)
            pa[kk] = *(const bf16x8*)(Ps + ((size_t)prowPV*8 + ((kk*4+g) ^ (prowPV & 7)))*8);
        __builtin_amdgcn_s_setprio(1);
        #pragma unroll
        for (int kk = 0; kk < 2; ++kk) {
            int vr = dt1*16 + lh;
            bf16x8 vf = *(const bf16x8*)(Vs + ((size_t)vr*8 + ((kk*4+g) ^ (vr & 7)))*8);
            accA = MFMA16(pa[kk], vf, accA);
        }
        if (two) {
            #pragma unroll
            for (int kk = 0; kk < 2; ++kk) {
                int vr = dt2*16 + lh;
                bf16x8 vf = *(const bf16x8*)(Vs + ((size_t)vr*8 + ((kk*4+g) ^ (vr & 7)))*8);
                accB = MFMA16(pa[kk], vf, accB);
            }
        }
        __builtin_amdgcn_s_setprio(0);
        __syncthreads();   // B1: Vs/Ps reads done

        // ds_write next V (ordered vs next PV reads by next iter's B2+B3)
        if (kt < 31) {
            *(float4*)(Vs + ((size_t)vr_s*8 + (vc_s ^ (vr_s & 7)))*8) = vp0;
            if (tid < 256)
                *(float4*)(Vs + ((size_t)vr2_s*8 + (vc2_s ^ (vr2_s & 7)))*8) = vp1;
        }
    }

    // ctx write (scaled by 1/l per row)
    float ils[4];
    #pragma unroll
    for (int r = 0; r < 4; ++r)
        ils[r] = 1.0f / lrow[(bh << 11) + q0 + rt*16 + g*4 + r];
    #pragma unroll
    for (int r = 0; r < 4; ++r) {
        int qrow = q0 + rt*16 + g*4 + r;
        ctxb[((size_t)(b*S_LEN + qrow))*EMB + h*HD + dt1*16 + lh] = f2bf(accA[r] * ils[r]);
        if (two)
            ctxb[((size_t)(b*S_LEN + qrow))*EMB + h*HD + dt2*16 + lh] = f2bf(accB[r] * ils[r]);
    }
}

// ---------------------------------------------------------------------------
// Output proj MFMA (64x64 tile)
// ---------------------------------------------------------------------------
__global__ __launch_bounds__(256) void out_mfma_kernel(
    const u16* __restrict__ ctxb, const u16* __restrict__ WoT,
    const float* __restrict__ bo, const float* __restrict__ hs,
    float* __restrict__ res)
{
    __shared__ __align__(16) u16 As[64*64];
    __shared__ __align__(16) u16 Bs[64*64];
    const int tid = threadIdx.x;
    const int w = tid >> 6, lane = tid & 63, lh = lane & 15, g = lane >> 4;
    const int wm = w >> 1, wn = w & 1;
    const int row0 = blockIdx.y * 64, col0 = blockIdx.x * 64;

    f32x4 acc[2][2];
    #pragma unroll
    for (int i = 0; i < 2; ++i)
        #pragma unroll
        for (int j = 0; j < 2; ++j) acc[i][j] = (f32x4){0.f,0.f,0.f,0.f};

    for (int k0 = 0; k0 < EMB; k0 += 64) {
        __syncthreads();
        #pragma unroll
        for (int i = 0; i < 2; ++i) {
            int idx = tid + 256*i;
            int r = idx >> 3, c = idx & 7;
            float4 a4 = *(const float4*)(ctxb + (size_t)(row0 + r)*EMB + k0 + c*8);
            *(float4*)(As + ((size_t)r*8 + (c ^ (r & 7)))*8) = a4;
            float4 b4 = *(const float4*)(WoT + (size_t)(col0 + r)*EMB + k0 + c*8);
            *(float4*)(Bs + ((size_t)r*8 + (c ^ (r & 7)))*8) = b4;
        }
        __syncthreads();
        bf16x8 af[2][2], bfr[2][2];
        #pragma unroll
        for (int mt = 0; mt < 2; ++mt)
            #pragma unroll
            for (int kk = 0; kk < 2; ++kk) {
                int r = wm*32 + mt*16 + lh;
                af[mt][kk] = *(const bf16x8*)(As + ((size_t)r*8 + ((kk*4+g) ^ (lh & 7)))*8);
            }
        #pragma unroll
        for (int nt = 0; nt < 2; ++nt)
            #pragma unroll
            for (int kk = 0; kk < 2; ++kk) {
                int r = wn*32 + nt*16 + lh;
                bfr[nt][kk] = *(const bf16x8*)(Bs + ((size_t)r*8 + ((kk*4+g) ^ (lh & 7)))*8);
            }
        #pragma unroll
        for (int mt = 0; mt < 2; ++mt)
            #pragma unroll
            for (int nt = 0; nt < 2; ++nt)
                #pragma unroll
                for (int kk = 0; kk < 2; ++kk)
                    acc[mt][nt] = MFMA16(af[mt][kk], bfr[nt][kk], acc[mt][nt]);
    }

    #pragma unroll
    for (int mt = 0; mt < 2; ++mt)
        #pragma unroll
        for (int nt = 0; nt < 2; ++nt)
            #pragma unroll
            for (int r = 0; r < 4; ++r) {
                int tt = row0 + wm*32 + mt*16 + g*4 + r;
                int o  = col0 + wn*32 + nt*16 + lh;
                res[(size_t)tt*EMB + o] = acc[mt][nt][r] + bo[o] + hs[(size_t)tt*EMB + o];
            }
}

// ---------------------------------------------------------------------------
// LayerNorm in place over last dim 768. grid NTOK, block 256.
// ---------------------------------------------------------------------------
__device__ __forceinline__ float block_sum256(float v, float* red) {
    #pragma unroll
    for (int off = 32; off > 0; off >>= 1) v += __shfl_down(v, off);
    int lane = threadIdx.x & 63, w = threadIdx.x >> 6;
    __syncthreads();
    if (lane == 0) red[w] = v;
    __syncthreads();
    return red[0] + red[1] + red[2] + red[3];
}

__global__ __launch_bounds__(256) void ln_kernel(
    float* __restrict__ res, const float* __restrict__ gamma, const float* __restrict__ beta)
{
    const int t = blockIdx.x;
    float* row = res + (size_t)t * EMB;
    const int tid = threadIdx.x;
    __shared__ float red[4];

    float x0 = row[tid], x1 = row[tid + 256], x2 = row[tid + 512];
    float s = block_sum256(x0 + x1 + x2, red);
    float mu = s * (1.0f / (float)EMB);
    float d0 = x0 - mu, d1 = x1 - mu, d2 = x2 - mu;
    float sq = block_sum256(d0*d0 + d1*d1 + d2*d2, red);
    float var = sq * (1.0f / (float)EMB);
    float scale = rsqrtf(var + 1e-5f);

    row[tid]       = d0 * scale * gamma[tid]       + beta[tid];
    row[tid + 256] = d1 * scale * gamma[tid + 256] + beta[tid + 256];
    row[tid + 512] = d2 * scale * gamma[tid + 512] + beta[tid + 512];
}

// ---------------------------------------------------------------------------
extern "C" void kernel_launch(void* const* d_in, const int* in_sizes, int n_in,
                              void* d_out, int out_size, void* d_ws, size_t ws_size,
                              hipStream_t stream)
{
    (void)in_sizes; (void)n_in; (void)out_size; (void)ws_size;

    const float* hs   = (const float*)d_in[0];
    const float* dist = (const float*)d_in[1];
    const float* ang  = (const float*)d_in[2];
    const float* mask = (const float*)d_in[3];
    const float* Wq = (const float*)d_in[4];  const float* bq = (const float*)d_in[5];
    const float* Wk = (const float*)d_in[6];  const float* bk = (const float*)d_in[7];
    const float* Wv = (const float*)d_in[8];  const float* bv = (const float*)d_in[9];
    const float* dw = (const float*)d_in[10]; const float* db = (const float*)d_in[11];
    const float* aw = (const float*)d_in[12]; const float* ab = (const float*)d_in[13];
    const float* Wo = (const float*)d_in[14]; const float* bo = (const float*)d_in[15];
    const float* gamma = (const float*)d_in[16]; const float* beta = (const float*)d_in[17];

    float* out   = (float*)d_out;                      // [B,S,E]
    float* probs = out + (size_t)NTOK * EMB;           // [B,H,S,S]

    u16* hsb = (u16*)d_ws;
    u16* WqT = hsb + (size_t)NTOK*EMB;
    u16* WkT = WqT + (size_t)EMB*EMB;
    u16* WvT = WkT + (size_t)EMB*EMB;
    u16* WoT = WvT + (size_t)EMB*EMB;
    u16* qb  = WoT + (size_t)EMB*EMB;
    u16* kb  = qb + (size_t)NTOK*EMB;
    u16* vb  = kb + (size_t)NTOK*EMB;
    u16* vtb = vb + (size_t)NTOK*EMB;
    u16* ctxb = qb;                                    // reuse q region after attn
    float* lrow = (float*)(vtb + (size_t)NTOK*EMB);

    cvt_bf16_kernel<<<dim3(NTOK*EMB/4/256), dim3(256), 0, stream>>>(hs, hsb, NTOK*EMB/4);
    transcvt4_kernel<<<dim3(12,12,4), dim3(256), 0, stream>>>(
        Wq, WqT, Wk, WkT, Wv, WvT, Wo, WoT);

    qkv_mfma_kernel<<<dim3(EMB/64, NTOK/64, 3), dim3(256), 0, stream>>>(
        hsb, WqT, bq, WkT, bk, WvT, bv, qb, kb, vb);

    vtrans_kernel<<<dim3(S_LEN/64, BATCH*NH), dim3(256), 0, stream>>>(vb, vtb);

    scores_l_kernel<<<dim3(S_LEN/32, BATCH*NH), dim3(512), 0, stream>>>(
        qb, kb, dist, ang, mask, dw, db, aw, ab, lrow);

    attn_pv_kernel<<<dim3(S_LEN/32, BATCH*NH), dim3(512), 0, stream>>>(
        qb, kb, vtb, dist, ang, mask, dw, db, aw, ab, lrow, probs, ctxb);

    out_mfma_kernel<<<dim3(EMB/64, NTOK/64), dim3(256), 0, stream>>>(
        ctxb, WoT, bo, hs, out);

    ln_kernel<<<dim3(NTOK), dim3(256), 0, stream>>>(out, gamma, beta);
}